// Round 16
// baseline (71.912 us; speedup 1.0000x reference)
//
#include <hip/hip_runtime.h>
#include <math.h>

#define A_    16
#define N_    1000
#define F_    16
#define E_    16000
#define D_    128
#define CAP_  48          // total in-degree cap (Binomial mean 16, 8 sigma)
#define MAXS  49          // slot 0 = self, 1..48 = in-edges of agent node
#define NB_A1 196         // attn1 blocks: 784 waves = 16*49
#define NB_GH 24          // gh blocks (6144 = 16*384 row-dots)
#define CHK   63          // edges per thread in block scan: 256*63 >= 16000

__device__ __forceinline__ float lrelu(float v){ return v > 0.0f ? v : 0.2f*v; }
__device__ __forceinline__ float sigm(float x){ return 1.0f/(1.0f + expf(-x)); }

// ---- D1: blocks 0-195 = self-contained attn1 (block-local edge scan ->
//          slot map + adjacency) + LN/ReLU + fused xl2/xr2 GEMV;
//          blocks 196-219 = gh = bhh + Whh @ rnn_state ---------------------
__global__ void __launch_bounds__(256) k_mid(
    const float* __restrict__ nf, const int* __restrict__ ei,
    const float* __restrict__ Wl1, const float* __restrict__ Wr1,
    const float* __restrict__ att1, const float* __restrict__ b1,
    const float* __restrict__ lnw, const float* __restrict__ lnb,
    const float* __restrict__ Wl2, const float* __restrict__ Wr2,
    const float* __restrict__ hs, const float* __restrict__ Whh,
    const float* __restrict__ bhh,
    float* __restrict__ xl2_c, float* __restrict__ xr2g,
    float* __restrict__ ghb){
  const int tid = threadIdx.x;

  if (blockIdx.x >= NB_A1){            // ---- gh rows (independent)
    const int rg = (blockIdx.x - NB_A1)*256 + tid;   // 0..6143
    const int a = rg/384, r = rg - a*384;
    const float4* w4 = (const float4*)&Whh[r*D_];
    const float4* x4 = (const float4*)&hs[a*D_];
    float acc = bhh[r];
    #pragma unroll
    for (int k = 0; k < D_/4; ++k){
      float4 w = w4[k], x = x4[k];
      acc += w.x*x.x + w.y*x.y + w.z*x.z + w.w*x.w;
    }
    ghb[a*384 + r] = acc;
    return;
  }

  const int bid  = blockIdx.x;
  const int lane = tid & 63;
  const int wv   = tid >> 6;
  const int wid  = bid*4 + wv;                // 0..783
  const int a_w  = wid / MAXS;
  const int i_w  = wid - a_w*MAXS;
  const int a0   = (bid*4) / MAXS;
  const int a1   = (bid*4 + 3) / MAXS;
  const int nag  = (a1 > a0) ? 2 : 1;

  __shared__ float feat[4][MAXS*F_];          // 12.5 KB (declare first: alignment)
  __shared__ int   sslot[2][MAXS];
  __shared__ int   nbrw[4][CAP_];
  __shared__ int   sh_da[2];
  __shared__ int   pc[2][4];
  __shared__ int   vnode[4];
  __shared__ int   ncw[4];

  // ---- pass 0: agent flags for the block's agents
  for (int g = 0; g < nag; ++g){
    const int ag = a0 + g;
    for (int t = tid; t < N_; t += 256)
      if (nf[(size_t)(ag*N_ + t)*F_] == 1.0f) sh_da[g] = t;
  }
  if (tid < 4) ncw[tid] = 0;
  __syncthreads();

  // ---- pass 1: count this thread's chunk matches per agent
  const int e0 = tid*CHK;
  int cnt[2] = {0, 0};
  for (int q = 0; q < CHK; ++q){
    const int e = e0 + q;
    if (e >= E_) break;
    const int dst = ei[E_ + e];
    if (dst == sh_da[0]) cnt[0]++;
    if (nag > 1 && dst == sh_da[1]) cnt[1]++;
  }
  // wave-level inclusive scan + wave totals -> deterministic edge-order prefix
  int pre[2];
  #pragma unroll
  for (int g = 0; g < 2; ++g){
    int x = cnt[g];
    #pragma unroll
    for (int off = 1; off < 64; off <<= 1){
      int y = __shfl_up(x, off);
      if (lane >= off) x += y;
    }
    if (lane == 63) pc[g][wv] = x;
    pre[g] = x - cnt[g];
  }
  __syncthreads();
  int degA[2];
  #pragma unroll
  for (int g = 0; g < 2; ++g){
    int base = 0, tot = 0;
    #pragma unroll
    for (int w2 = 0; w2 < 4; ++w2){ if (w2 < wv) base += pc[g][w2]; tot += pc[g][w2]; }
    pre[g] += base; degA[g] = tot;
  }

  // ---- pass 1b: emit slot srcs at deterministic ordinals
  {
    int o0 = pre[0], o1 = pre[1];
    for (int q = 0; q < CHK; ++q){
      const int e = e0 + q;
      if (e >= E_) break;
      const int dst = ei[E_ + e];
      if (dst == sh_da[0]){ if (o0 < MAXS-1) sslot[0][1 + o0] = ei[e]; o0++; }
      if (nag > 1 && dst == sh_da[1]){ if (o1 < MAXS-1) sslot[1][1 + o1] = ei[e]; o1++; }
    }
  }
  if (tid < nag) sslot[tid][0] = sh_da[tid];
  __syncthreads();

  // ---- wave's node
  const int g_w  = a_w - a0;
  const int dega = min(degA[g_w], MAXS-1);
  const bool active = (i_w <= dega);
  const int v = active ? sslot[g_w][i_w] : -1;
  if (lane == 0) vnode[wv] = v;
  __syncthreads();

  // ---- pass 2: in-neighbor lists for the block's 4 wave nodes
  for (int q = 0; q < CHK; ++q){
    const int e = e0 + q;
    if (e >= E_) break;
    const int dst = ei[E_ + e];
    #pragma unroll
    for (int w2 = 0; w2 < 4; ++w2){
      if (dst == vnode[w2]){
        int pos = atomicAdd(&ncw[w2], 1);
        if (pos < CAP_) nbrw[w2][pos] = ei[e];
      }
    }
  }
  __syncthreads();
  if (!active) return;
  const int a   = a_w;
  const int deg = min(ncw[wv], CAP_);
  const int c0  = lane*2;
  float* fb = feat[wv];

  // ---- stage feature rows: 0=self, 1..deg = neighbors
  for (int t = lane; t < (deg+1)*4; t += 64){
    int j = t >> 2, q = (t & 3)*4;
    int s = (j == 0) ? v : nbrw[wv][j-1];
    *(float4*)&fb[j*F_ + q] = *(const float4*)&nf[((size_t)a*N_ + s)*F_ + q];
  }
  asm volatile("s_waitcnt lgkmcnt(0)" ::: "memory");

  float wl0[F_], wl1c[F_];
  #pragma unroll
  for (int k = 0; k < F_; ++k){
    float2 w = *(const float2*)&Wl1[k*D_ + c0];
    wl0[k] = w.x; wl1c[k] = w.y;
  }
  float xr0 = 0.f, xr1 = 0.f;
  #pragma unroll
  for (int k = 0; k < F_; ++k){
    float2 w = *(const float2*)&Wr1[k*D_ + c0];
    float xv = fb[k];
    xr0 += xv*w.x; xr1 += xv*w.y;
  }
  const int head = lane >> 4;
  const float at0 = att1[head*32 + (c0 & 31)];
  const float at1 = att1[head*32 + ((c0+1) & 31)];

  float m = -INFINITY, ls = 0.f, ac0 = 0.f, ac1 = 0.f;
  for (int j = 0; j <= deg; ++j){
    const float* fr = &fb[j*F_];
    float xl0 = 0.f, xl1 = 0.f;
    #pragma unroll
    for (int k = 0; k < F_; k += 4){
      float4 xv = *(const float4*)&fr[k];
      xl0 += xv.x*wl0[k]  + xv.y*wl0[k+1]  + xv.z*wl0[k+2]  + xv.w*wl0[k+3];
      xl1 += xv.x*wl1c[k] + xv.y*wl1c[k+1] + xv.z*wl1c[k+2] + xv.w*wl1c[k+3];
    }
    float t = lrelu(xl0 + xr0)*at0 + lrelu(xl1 + xr1)*at1;
    t += __shfl_xor(t,1); t += __shfl_xor(t,2);
    t += __shfl_xor(t,4); t += __shfl_xor(t,8);         // 16-lane head groups
    float mn = fmaxf(m, t);
    float sc = expf(m - mn), p = expf(t - mn);
    ls = ls*sc + p; ac0 = ac0*sc + p*xl0; ac1 = ac1*sc + p*xl1;
    m = mn;
  }
  float inv = 1.0f/ls;
  float v0 = ac0*inv + b1[c0], v1 = ac1*inv + b1[c0+1];
  float ss = v0 + v1;
  ss += __shfl_xor(ss,1); ss += __shfl_xor(ss,2); ss += __shfl_xor(ss,4);
  ss += __shfl_xor(ss,8); ss += __shfl_xor(ss,16); ss += __shfl_xor(ss,32);
  float mu = ss*(1.0f/D_);
  float d0 = v0 - mu, d1 = v1 - mu;
  float vs = d0*d0 + d1*d1;
  vs += __shfl_xor(vs,1); vs += __shfl_xor(vs,2); vs += __shfl_xor(vs,4);
  vs += __shfl_xor(vs,8); vs += __shfl_xor(vs,16); vs += __shfl_xor(vs,32);
  float rinv = rsqrtf(vs*(1.0f/D_) + 1e-5f);
  float h0 = fmaxf(d0*rinv*lnw[c0]   + lnb[c0],   0.0f);
  float h1 = fmaxf(d1*rinv*lnw[c0+1] + lnb[c0+1], 0.0f);

  // ---- fused epilogue: park h row in wave-local LDS, xl2 = h @ Wl2
  fb[c0] = h0; fb[c0+1] = h1;
  asm volatile("s_waitcnt lgkmcnt(0)" ::: "memory");    // wave-coherent LDS

  float xa0 = 0.f, xa1 = 0.f;
  #pragma unroll 8
  for (int k = 0; k < D_; k += 4){
    float4 hv = *(const float4*)&fb[k];
    float2 w0 = *(const float2*)&Wl2[(k+0)*D_ + c0];
    float2 w1 = *(const float2*)&Wl2[(k+1)*D_ + c0];
    float2 w2 = *(const float2*)&Wl2[(k+2)*D_ + c0];
    float2 w3 = *(const float2*)&Wl2[(k+3)*D_ + c0];
    xa0 += hv.x*w0.x + hv.y*w1.x + hv.z*w2.x + hv.w*w3.x;
    xa1 += hv.x*w0.y + hv.y*w1.y + hv.z*w2.y + hv.w*w3.y;
  }
  *(float2*)&xl2_c[((size_t)a*MAXS + i_w)*D_ + c0] = make_float2(xa0, xa1);

  if (i_w == 0){                       // agent slot also produces xr2
    float xb0 = 0.f, xb1 = 0.f;
    #pragma unroll 8
    for (int k = 0; k < D_; k += 4){
      float4 hv = *(const float4*)&fb[k];
      float2 w0 = *(const float2*)&Wr2[(k+0)*D_ + c0];
      float2 w1 = *(const float2*)&Wr2[(k+1)*D_ + c0];
      float2 w2 = *(const float2*)&Wr2[(k+2)*D_ + c0];
      float2 w3 = *(const float2*)&Wr2[(k+3)*D_ + c0];
      xb0 += hv.x*w0.x + hv.y*w1.x + hv.z*w2.x + hv.w*w3.x;
      xb1 += hv.x*w0.y + hv.y*w1.y + hv.z*w2.y + hv.w*w3.y;
    }
    *(float2*)&xr2g[a*D_ + c0] = make_float2(xb0, xb1);
  }
}

// ---- D2: per-agent tail: attn2 + gi + GRU + heads (self-contained) -------
__global__ void __launch_bounds__(1024) k_tail(
    const float* __restrict__ xl2_c, const float* __restrict__ xr2g,
    const float* __restrict__ ghb,
    const float* __restrict__ nf, const int* __restrict__ ei,
    const float* __restrict__ hs, const int* __restrict__ am,
    const float* __restrict__ att2, const float* __restrict__ b2,
    const float* __restrict__ Wih, const float* __restrict__ bih,
    const float* __restrict__ Wa, const float* __restrict__ ba,
    const float* __restrict__ Wv, const float* __restrict__ bv,
    float* __restrict__ out){
  const int a    = blockIdx.x;
  const int tid  = threadIdx.x;
  const int lane = tid & 63;
  const int wv   = tid >> 6;

  __shared__ float xsl[MAXS][D_];      // xl2 rows
  __shared__ float xr2s[D_], afl[D_], ghl[3*D_], gbuf[3*D_], hsrow[D_], nh[D_];
  __shared__ float scores[64];
  __shared__ int   sh_da, sh_cnt;

  // find agent node + in-degree (self-contained, no scan kernel)
  if (tid == 0) sh_cnt = 0;
  if (tid < N_ && nf[(size_t)(a*N_ + tid)*F_] == 1.0f) sh_da = tid;
  __syncthreads();
  const int d_a = sh_da;
  {
    int c = 0;
    #pragma unroll
    for (int q = 0; q < 16; ++q){
      const int e = q*1024 + tid;
      if (e < E_ && ei[E_ + e] == d_a) c++;
    }
    c += __shfl_xor(c,1);  c += __shfl_xor(c,2);  c += __shfl_xor(c,4);
    c += __shfl_xor(c,8);  c += __shfl_xor(c,16); c += __shfl_xor(c,32);
    if (lane == 0 && c) atomicAdd(&sh_cnt, c);
  }
  // T0: stage xl2 rows (cap MAXS) + xr2 + gh + rnn_state
  if (tid < D_) hsrow[tid] = hs[a*D_ + tid];
  else if (tid < 4*D_) ghl[tid - D_] = ghb[a*384 + (tid - D_)];
  else if (tid < 5*D_) xr2s[tid - 4*D_] = xr2g[a*D_ + (tid - 4*D_)];
  __syncthreads();
  const int ns = min(sh_cnt, CAP_) + 1;
  for (int t = tid; t < ns*(D_/4); t += 1024){
    int j = t >> 5, q = t & 31;
    ((float4*)xsl[j])[q] = ((const float4*)&xl2_c[((size_t)a*MAXS + j)*D_])[q];
  }
  __syncthreads();

  // T2a: attention scores, wave w handles slots w, w+16, w+32, w+48
  {
    const int c0 = lane*2;
    const float xr0 = xr2s[c0], xr1 = xr2s[c0+1];
    const float at0 = att2[c0], at1 = att2[c0+1];
    for (int q = 0; q < 4; ++q){
      const int s = wv + q*16;
      if (s < ns){
        float2 xl = *(const float2*)&xsl[s][c0];
        float t = lrelu(xl.x + xr0)*at0 + lrelu(xl.y + xr1)*at1;
        t += __shfl_xor(t,1);  t += __shfl_xor(t,2);  t += __shfl_xor(t,4);
        t += __shfl_xor(t,8);  t += __shfl_xor(t,16); t += __shfl_xor(t,32);
        if (lane == 0) scores[s] = t;
      }
    }
  }
  __syncthreads();
  // T2b: softmax over ns scores (wave 0, lane-parallel)
  if (wv == 0){
    float sc = (lane < ns) ? scores[lane] : -INFINITY;
    float m = sc;
    m = fmaxf(m, __shfl_xor(m,1));  m = fmaxf(m, __shfl_xor(m,2));
    m = fmaxf(m, __shfl_xor(m,4));  m = fmaxf(m, __shfl_xor(m,8));
    m = fmaxf(m, __shfl_xor(m,16)); m = fmaxf(m, __shfl_xor(m,32));
    float p = (lane < ns) ? expf(sc - m) : 0.f;
    float s = p;
    s += __shfl_xor(s,1);  s += __shfl_xor(s,2);  s += __shfl_xor(s,4);
    s += __shfl_xor(s,8);  s += __shfl_xor(s,16); s += __shfl_xor(s,32);
    if (lane < ns) scores[lane] = p/s;           // alpha
  }
  __syncthreads();
  // T2c: weighted sum -> afl
  if (tid < D_){
    float acc = 0.f;
    for (int i = 0; i < ns; ++i) acc += scores[i]*xsl[i][tid];
    afl[tid] = acc + b2[tid];
  }
  __syncthreads();

  // T3: gi = bih + Wih @ afl — 8 lanes per row, coalesced float4 reads
  #pragma unroll
  for (int p = 0; p < 3; ++p){
    const int r  = p*128 + (tid >> 3);
    const int kk = (tid & 7)*16;
    const float4* w4 = (const float4*)&Wih[r*D_ + kk];
    float acc = 0.f;
    #pragma unroll
    for (int q = 0; q < 4; ++q){
      float4 w = w4[q];
      float4 x = *(const float4*)&afl[kk + q*4];
      acc += w.x*x.x + w.y*x.y + w.z*x.z + w.w*x.w;
    }
    acc += __shfl_xor(acc,1); acc += __shfl_xor(acc,2); acc += __shfl_xor(acc,4);
    if ((tid & 7) == 0) gbuf[r] = acc + bih[r];
  }
  __syncthreads();

  // T4: GRU elementwise
  if (tid < D_){
    float r = sigm(gbuf[tid]         + ghl[tid]);
    float z = sigm(gbuf[D_ + tid]    + ghl[D_ + tid]);
    float n = tanhf(gbuf[2*D_ + tid] + r*ghl[2*D_ + tid]);
    float nv = (1.0f - z)*n + z*hsrow[tid];
    nh[tid] = nv;
    out[272 + a*D_ + tid] = nv;                  // next_h
  }
  __syncthreads();

  // T5: heads, wave-parallel
  if (wv == 0){
    const int j = lane & 15, q = lane >> 4;      // action j, k-quarter q
    float acc = 0.f;
    #pragma unroll 8
    for (int k = q*32; k < q*32 + 32; ++k) acc += nh[k]*Wa[k*16 + j];
    acc += __shfl_xor(acc,16); acc += __shfl_xor(acc,32);
    if (lane < 16){
      float lg = acc + ba[j];
      if (am[a*16 + j] == 0) lg = -1e8f;
      out[a*16 + j] = lg;                        // logits
    }
  } else if (wv == 1){
    const int c0 = lane*2;
    float acc = nh[c0]*Wv[c0] + nh[c0+1]*Wv[c0+1];
    acc += __shfl_xor(acc,1);  acc += __shfl_xor(acc,2);  acc += __shfl_xor(acc,4);
    acc += __shfl_xor(acc,8);  acc += __shfl_xor(acc,16); acc += __shfl_xor(acc,32);
    if (lane == 0) out[256 + a] = acc + bv[0];   // values
  }
}

// ---------------------------------------------------------------------------
extern "C" void kernel_launch(void* const* d_in, const int* in_sizes, int n_in,
                              void* d_out, int out_size, void* d_ws, size_t ws_size,
                              hipStream_t stream){
  const float* nf   = (const float*)d_in[0];
  const int*   ei   = (const int*)  d_in[1];
  const float* hs   = (const float*)d_in[2];
  const int*   am   = (const int*)  d_in[3];
  const float* Wl1  = (const float*)d_in[4];
  const float* Wr1  = (const float*)d_in[5];
  const float* att1 = (const float*)d_in[6];
  const float* b1   = (const float*)d_in[7];
  const float* lnw  = (const float*)d_in[8];
  const float* lnb  = (const float*)d_in[9];
  const float* Wl2  = (const float*)d_in[10];
  const float* Wr2  = (const float*)d_in[11];
  const float* att2 = (const float*)d_in[12];
  const float* b2   = (const float*)d_in[13];
  const float* Wih  = (const float*)d_in[14];
  const float* Whh  = (const float*)d_in[15];
  const float* bih  = (const float*)d_in[16];
  const float* bhh  = (const float*)d_in[17];
  const float* Wa   = (const float*)d_in[18];
  const float* ba   = (const float*)d_in[19];
  const float* Wv   = (const float*)d_in[20];
  const float* bv   = (const float*)d_in[21];
  float* out = (float*)d_out;

  float* wsF = (float*)d_ws;
  float* xl2_c = wsF;                 // 16*49*128 floats -> 100352
  float* xr2g  = wsF + 100352;        // 16*128 floats
  float* ghb   = wsF + 102400;        // 16*384 floats

  k_mid <<<NB_A1 + NB_GH, 256, 0, stream>>>(nf, ei, Wl1, Wr1, att1, b1, lnw, lnb,
                                            Wl2, Wr2, hs, Whh, bhh,
                                            xl2_c, xr2g, ghb);
  k_tail<<<A_, 1024, 0, stream>>>(xl2_c, xr2g, ghb, nf, ei, hs, am,
                                  att2, b2, Wih, bih, Wa, ba, Wv, bv, out);
}

// Round 17
// 34.946 us; speedup vs baseline: 2.0578x; 2.0578x over previous
//
#include <hip/hip_runtime.h>
#include <math.h>

#define A_    16
#define N_    1000
#define F_    16
#define E_    16000
#define D_    128
#define SEG_  8           // scan segments (one block each, private LDS histogram)
#define EPB   2000        // edges per scan block: 8*2000 = 16000
#define CAPS  16          // per-(node,segment) capacity (mean 2, ~9 sigma)
#define CAP_  48          // total in-degree cap (Binomial mean 16, 8 sigma)
#define MAXS  49          // slot 0 = self, 1..48 = in-edges of agent node
#define NB_A1 196         // attn1 blocks: 784 waves = 16*49
#define NB_GH 24          // gh blocks (6144 = 16*384 row-dots)

__device__ __forceinline__ float lrelu(float v){ return v > 0.0f ? v : 0.2f*v; }
__device__ __forceinline__ float sigm(float x){ return 1.0f/(1.0f + expf(-x)); }

__device__ __forceinline__ int seg_total(const int* __restrict__ ncnt, int v){
  int t = 0;
  #pragma unroll
  for (int s = 0; s < SEG_; ++s) t += ncnt[v*SEG_ + s];
  return t;
}
// ordinal j (0-based) among v's in-edges -> source node id
__device__ __forceinline__ int seg_lookup(const int* __restrict__ ncnt,
                                          const int* __restrict__ nbrs, int v, int j){
  int base = 0, r = 0;
  bool done = false;
  #pragma unroll
  for (int s = 0; s < SEG_; ++s){
    int c = ncnt[v*SEG_ + s];
    if (!done && j < base + c){ r = nbrs[(v*SEG_ + s)*CAPS + (j - base)]; done = true; }
    base += c;
  }
  return r;
}

// ---- D1: blocks 0-7 segmented edge scan | 8-23 agent flags | 24-47 gh ----
__global__ void __launch_bounds__(256) k_pre(
    const int* __restrict__ ei, const float* __restrict__ nf,
    const float* __restrict__ hs, const float* __restrict__ Whh,
    const float* __restrict__ bhh,
    int* __restrict__ ncnt, int* __restrict__ nbrs,
    int* __restrict__ agent_node, float* __restrict__ ghb){
  const int bid = blockIdx.x, tid = threadIdx.x;

  if (bid < SEG_){                     // private-LDS histogram over own slice
    __shared__ int lcnt[N_];
    for (int t = tid; t < N_; t += 256) lcnt[t] = 0;
    __syncthreads();
    const int base = bid*EPB;
    #pragma unroll
    for (int r = 0; r < 8; ++r){
      const int e = base + r*256 + tid;
      if (e < base + EPB && e < E_){
        int src = ei[e], dst = ei[E_ + e];
        int pos = atomicAdd(&lcnt[dst], 1);
        if (pos < CAPS) nbrs[(dst*SEG_ + bid)*CAPS + pos] = src;
      }
    }
    __syncthreads();
    for (int t = tid; t < N_; t += 256) ncnt[t*SEG_ + bid] = min(lcnt[t], CAPS);
  } else if (bid < SEG_ + A_){         // agent flag scan (one block per agent)
    const int a = bid - SEG_;
    for (int t = tid; t < N_; t += 256)
      if (nf[(size_t)(a*N_ + t)*F_] == 1.0f) agent_node[a] = t;
  } else {                             // gh = bhh + Whh @ rnn_state
    const int rg = (bid - SEG_ - A_)*256 + tid;      // 0..6143
    const int a = rg/384, r = rg - a*384;
    const float4* w4 = (const float4*)&Whh[r*D_];
    const float4* x4 = (const float4*)&hs[a*D_];
    float acc = bhh[r];
    #pragma unroll
    for (int k = 0; k < D_/4; ++k){
      float4 w = w4[k], x = x4[k];
      acc += w.x*x.x + w.y*x.y + w.z*x.z + w.w*x.w;
    }
    ghb[a*384 + r] = acc;
  }
}

// ---- D2: layer-1 GATv2 + LN/ReLU + fused xl2/xr2 GEMV (196 blocks) -------
__global__ void __launch_bounds__(256) k_mid(
    const float* __restrict__ nf, const int* __restrict__ agent_node,
    const int* __restrict__ ncnt, const int* __restrict__ nbrs,
    const float* __restrict__ Wl1, const float* __restrict__ Wr1,
    const float* __restrict__ att1, const float* __restrict__ b1,
    const float* __restrict__ lnw, const float* __restrict__ lnb,
    const float* __restrict__ Wl2, const float* __restrict__ Wr2,
    float* __restrict__ xl2_c, float* __restrict__ xr2g){
  const int tid  = threadIdx.x;
  const int lane = tid & 63;
  const int wv   = tid >> 6;
  const int wid  = blockIdx.x*4 + wv;
  const int a = wid / MAXS;
  const int i = wid - a*MAXS;
  const int d_a  = agent_node[a];
  const int dega = min(seg_total(ncnt, d_a), CAP_);
  if (i > dega) return;
  const int v   = (i == 0) ? d_a : seg_lookup(ncnt, nbrs, d_a, i-1);
  const int deg = min(seg_total(ncnt, v), CAP_);
  const int c0  = lane*2;

  __shared__ float feat[4][MAXS*F_];
  float* fb = feat[wv];

  int nid = (lane < deg) ? seg_lookup(ncnt, nbrs, v, lane) : 0;
  for (int t = lane; t < (deg+1)*4; t += 64){     // rows: 0=self, 1..deg
    int j = t >> 2, q = (t & 3)*4;
    int s = (j == 0) ? v : __shfl(nid, j-1);
    *(float4*)&fb[j*F_ + q] = *(const float4*)&nf[((size_t)a*N_ + s)*F_ + q];
  }
  asm volatile("s_waitcnt lgkmcnt(0)" ::: "memory");

  float wl0[F_], wl1c[F_];
  #pragma unroll
  for (int k = 0; k < F_; ++k){
    float2 w = *(const float2*)&Wl1[k*D_ + c0];
    wl0[k] = w.x; wl1c[k] = w.y;
  }
  float xr0 = 0.f, xr1 = 0.f;
  #pragma unroll
  for (int k = 0; k < F_; ++k){
    float2 w = *(const float2*)&Wr1[k*D_ + c0];
    float xv = fb[k];
    xr0 += xv*w.x; xr1 += xv*w.y;
  }
  const int head = lane >> 4;
  const float at0 = att1[head*32 + (c0 & 31)];
  const float at1 = att1[head*32 + ((c0+1) & 31)];

  float m = -INFINITY, ls = 0.f, ac0 = 0.f, ac1 = 0.f;
  for (int j = 0; j <= deg; ++j){
    const float* fr = &fb[j*F_];
    float xl0 = 0.f, xl1 = 0.f;
    #pragma unroll
    for (int k = 0; k < F_; k += 4){
      float4 xv = *(const float4*)&fr[k];
      xl0 += xv.x*wl0[k]  + xv.y*wl0[k+1]  + xv.z*wl0[k+2]  + xv.w*wl0[k+3];
      xl1 += xv.x*wl1c[k] + xv.y*wl1c[k+1] + xv.z*wl1c[k+2] + xv.w*wl1c[k+3];
    }
    float t = lrelu(xl0 + xr0)*at0 + lrelu(xl1 + xr1)*at1;
    t += __shfl_xor(t,1); t += __shfl_xor(t,2);
    t += __shfl_xor(t,4); t += __shfl_xor(t,8);         // 16-lane head groups
    float mn = fmaxf(m, t);
    float sc = expf(m - mn), p = expf(t - mn);
    ls = ls*sc + p; ac0 = ac0*sc + p*xl0; ac1 = ac1*sc + p*xl1;
    m = mn;
  }
  float inv = 1.0f/ls;
  float v0 = ac0*inv + b1[c0], v1 = ac1*inv + b1[c0+1];
  float ss = v0 + v1;
  ss += __shfl_xor(ss,1); ss += __shfl_xor(ss,2); ss += __shfl_xor(ss,4);
  ss += __shfl_xor(ss,8); ss += __shfl_xor(ss,16); ss += __shfl_xor(ss,32);
  float mu = ss*(1.0f/D_);
  float d0 = v0 - mu, d1 = v1 - mu;
  float vs = d0*d0 + d1*d1;
  vs += __shfl_xor(vs,1); vs += __shfl_xor(vs,2); vs += __shfl_xor(vs,4);
  vs += __shfl_xor(vs,8); vs += __shfl_xor(vs,16); vs += __shfl_xor(vs,32);
  float rinv = rsqrtf(vs*(1.0f/D_) + 1e-5f);
  float h0 = fmaxf(d0*rinv*lnw[c0]   + lnb[c0],   0.0f);
  float h1 = fmaxf(d1*rinv*lnw[c0+1] + lnb[c0+1], 0.0f);

  // ---- fused epilogue: park h row in wave-local LDS, xl2 = h @ Wl2 -------
  fb[c0] = h0; fb[c0+1] = h1;
  asm volatile("s_waitcnt lgkmcnt(0)" ::: "memory");    // wave-coherent LDS

  float xa0 = 0.f, xa1 = 0.f;
  #pragma unroll 8
  for (int k = 0; k < D_; k += 4){
    float4 hv = *(const float4*)&fb[k];
    float2 w0 = *(const float2*)&Wl2[(k+0)*D_ + c0];
    float2 w1 = *(const float2*)&Wl2[(k+1)*D_ + c0];
    float2 w2 = *(const float2*)&Wl2[(k+2)*D_ + c0];
    float2 w3 = *(const float2*)&Wl2[(k+3)*D_ + c0];
    xa0 += hv.x*w0.x + hv.y*w1.x + hv.z*w2.x + hv.w*w3.x;
    xa1 += hv.x*w0.y + hv.y*w1.y + hv.z*w2.y + hv.w*w3.y;
  }
  *(float2*)&xl2_c[((size_t)a*MAXS + i)*D_ + c0] = make_float2(xa0, xa1);

  if (i == 0){                         // agent slot also produces xr2
    float xb0 = 0.f, xb1 = 0.f;
    #pragma unroll 8
    for (int k = 0; k < D_; k += 4){
      float4 hv = *(const float4*)&fb[k];
      float2 w0 = *(const float2*)&Wr2[(k+0)*D_ + c0];
      float2 w1 = *(const float2*)&Wr2[(k+1)*D_ + c0];
      float2 w2 = *(const float2*)&Wr2[(k+2)*D_ + c0];
      float2 w3 = *(const float2*)&Wr2[(k+3)*D_ + c0];
      xb0 += hv.x*w0.x + hv.y*w1.x + hv.z*w2.x + hv.w*w3.x;
      xb1 += hv.x*w0.y + hv.y*w1.y + hv.z*w2.y + hv.w*w3.y;
    }
    *(float2*)&xr2g[a*D_ + c0] = make_float2(xb0, xb1);
  }
}

// ---- D3: per-agent tail: attn2 + gi + GRU + heads ------------------------
__global__ void __launch_bounds__(1024) k_tail(
    const float* __restrict__ xl2_c, const float* __restrict__ xr2g,
    const float* __restrict__ ghb,
    const int* __restrict__ agent_node, const int* __restrict__ ncnt,
    const float* __restrict__ hs, const int* __restrict__ am,
    const float* __restrict__ att2, const float* __restrict__ b2,
    const float* __restrict__ Wih, const float* __restrict__ bih,
    const float* __restrict__ Wa, const float* __restrict__ ba,
    const float* __restrict__ Wv, const float* __restrict__ bv,
    float* __restrict__ out){
  const int a    = blockIdx.x;
  const int tid  = threadIdx.x;
  const int lane = tid & 63;
  const int wv   = tid >> 6;

  __shared__ float xsl[MAXS][D_];      // xl2 rows
  __shared__ float xr2s[D_], afl[D_], ghl[3*D_], gbuf[3*D_], hsrow[D_], nh[D_];
  __shared__ float scores[64];

  const int d_a = agent_node[a];
  const int ns  = min(seg_total(ncnt, d_a), CAP_) + 1;

  // T0: stage xl2 rows + xr2 + gh + rnn_state
  for (int t = tid; t < ns*(D_/4); t += 1024){
    int j = t >> 5, q = t & 31;
    ((float4*)xsl[j])[q] = ((const float4*)&xl2_c[((size_t)a*MAXS + j)*D_])[q];
  }
  if (tid < D_) hsrow[tid] = hs[a*D_ + tid];
  else if (tid < 4*D_) ghl[tid - D_] = ghb[a*384 + (tid - D_)];
  else if (tid < 5*D_) xr2s[tid - 4*D_] = xr2g[a*D_ + (tid - 4*D_)];
  __syncthreads();

  // T2a: attention scores, wave w handles slots w, w+16, w+32, w+48
  {
    const int c0 = lane*2;
    const float xr0 = xr2s[c0], xr1 = xr2s[c0+1];
    const float at0 = att2[c0], at1 = att2[c0+1];
    for (int q = 0; q < 4; ++q){
      const int s = wv + q*16;
      if (s < ns){
        float2 xl = *(const float2*)&xsl[s][c0];
        float t = lrelu(xl.x + xr0)*at0 + lrelu(xl.y + xr1)*at1;
        t += __shfl_xor(t,1);  t += __shfl_xor(t,2);  t += __shfl_xor(t,4);
        t += __shfl_xor(t,8);  t += __shfl_xor(t,16); t += __shfl_xor(t,32);
        if (lane == 0) scores[s] = t;
      }
    }
  }
  __syncthreads();
  // T2b: softmax over ns scores (wave 0, lane-parallel)
  if (wv == 0){
    float sc = (lane < ns) ? scores[lane] : -INFINITY;
    float m = sc;
    m = fmaxf(m, __shfl_xor(m,1));  m = fmaxf(m, __shfl_xor(m,2));
    m = fmaxf(m, __shfl_xor(m,4));  m = fmaxf(m, __shfl_xor(m,8));
    m = fmaxf(m, __shfl_xor(m,16)); m = fmaxf(m, __shfl_xor(m,32));
    float p = (lane < ns) ? expf(sc - m) : 0.f;
    float s = p;
    s += __shfl_xor(s,1);  s += __shfl_xor(s,2);  s += __shfl_xor(s,4);
    s += __shfl_xor(s,8);  s += __shfl_xor(s,16); s += __shfl_xor(s,32);
    if (lane < ns) scores[lane] = p/s;           // alpha
  }
  __syncthreads();
  // T2c: weighted sum -> afl
  if (tid < D_){
    float acc = 0.f;
    for (int i = 0; i < ns; ++i) acc += scores[i]*xsl[i][tid];
    afl[tid] = acc + b2[tid];
  }
  __syncthreads();

  // T3: gi = bih + Wih @ afl — 8 lanes per row, coalesced float4 reads
  #pragma unroll
  for (int p = 0; p < 3; ++p){
    const int r  = p*128 + (tid >> 3);
    const int kk = (tid & 7)*16;
    const float4* w4 = (const float4*)&Wih[r*D_ + kk];
    float acc = 0.f;
    #pragma unroll
    for (int q = 0; q < 4; ++q){
      float4 w = w4[q];
      float4 x = *(const float4*)&afl[kk + q*4];
      acc += w.x*x.x + w.y*x.y + w.z*x.z + w.w*x.w;
    }
    acc += __shfl_xor(acc,1); acc += __shfl_xor(acc,2); acc += __shfl_xor(acc,4);
    if ((tid & 7) == 0) gbuf[r] = acc + bih[r];
  }
  __syncthreads();

  // T4: GRU elementwise
  if (tid < D_){
    float r = sigm(gbuf[tid]         + ghl[tid]);
    float z = sigm(gbuf[D_ + tid]    + ghl[D_ + tid]);
    float n = tanhf(gbuf[2*D_ + tid] + r*ghl[2*D_ + tid]);
    float nv = (1.0f - z)*n + z*hsrow[tid];
    nh[tid] = nv;
    out[272 + a*D_ + tid] = nv;                  // next_h
  }
  __syncthreads();

  // T5: heads, wave-parallel
  if (wv == 0){
    const int j = lane & 15, q = lane >> 4;      // action j, k-quarter q
    float acc = 0.f;
    #pragma unroll 8
    for (int k = q*32; k < q*32 + 32; ++k) acc += nh[k]*Wa[k*16 + j];
    acc += __shfl_xor(acc,16); acc += __shfl_xor(acc,32);
    if (lane < 16){
      float lg = acc + ba[j];
      if (am[a*16 + j] == 0) lg = -1e8f;
      out[a*16 + j] = lg;                        // logits
    }
  } else if (wv == 1){
    const int c0 = lane*2;
    float acc = nh[c0]*Wv[c0] + nh[c0+1]*Wv[c0+1];
    acc += __shfl_xor(acc,1);  acc += __shfl_xor(acc,2);  acc += __shfl_xor(acc,4);
    acc += __shfl_xor(acc,8);  acc += __shfl_xor(acc,16); acc += __shfl_xor(acc,32);
    if (lane == 0) out[256 + a] = acc + bv[0];   // values
  }
}

// ---------------------------------------------------------------------------
extern "C" void kernel_launch(void* const* d_in, const int* in_sizes, int n_in,
                              void* d_out, int out_size, void* d_ws, size_t ws_size,
                              hipStream_t stream){
  const float* nf   = (const float*)d_in[0];
  const int*   ei   = (const int*)  d_in[1];
  const float* hs   = (const float*)d_in[2];
  const int*   am   = (const int*)  d_in[3];
  const float* Wl1  = (const float*)d_in[4];
  const float* Wr1  = (const float*)d_in[5];
  const float* att1 = (const float*)d_in[6];
  const float* b1   = (const float*)d_in[7];
  const float* lnw  = (const float*)d_in[8];
  const float* lnb  = (const float*)d_in[9];
  const float* Wl2  = (const float*)d_in[10];
  const float* Wr2  = (const float*)d_in[11];
  const float* att2 = (const float*)d_in[12];
  const float* b2   = (const float*)d_in[13];
  const float* Wih  = (const float*)d_in[14];
  const float* Whh  = (const float*)d_in[15];
  const float* bih  = (const float*)d_in[16];
  const float* bhh  = (const float*)d_in[17];
  const float* Wa   = (const float*)d_in[18];
  const float* ba   = (const float*)d_in[19];
  const float* Wv   = (const float*)d_in[20];
  const float* bv   = (const float*)d_in[21];
  float* out = (float*)d_out;

  int* wsI = (int*)d_ws;
  int*   ncnt       = wsI;                      // [1000][8] ints
  int*   agent_node = wsI + 8000;               // 16 ints (pad to 8192)
  int*   nbrs       = wsI + 8192;               // [1000][8][16] ints -> ends 136192
  float* xl2_c      = (float*)(wsI + 136192);   // 16*49*128 floats -> ends 236544
  float* xr2g       = (float*)(wsI + 236544);   // 16*128 floats -> ends 238592
  float* ghb        = (float*)(wsI + 238592);   // 16*384 floats -> ends 244736

  k_pre <<<SEG_ + A_ + NB_GH, 256, 0, stream>>>(ei, nf, hs, Whh, bhh,
                                                ncnt, nbrs, agent_node, ghb);
  k_mid <<<NB_A1, 256, 0, stream>>>(nf, agent_node, ncnt, nbrs,
                                    Wl1, Wr1, att1, b1, lnw, lnb,
                                    Wl2, Wr2, xl2_c, xr2g);
  k_tail<<<A_, 1024, 0, stream>>>(xl2_c, xr2g, ghb, agent_node, ncnt, hs, am,
                                  att2, b2, Wih, bih, Wa, ba, Wv, bv, out);
}

// Round 18
// 33.987 us; speedup vs baseline: 2.1159x; 1.0282x over previous
//
#include <hip/hip_runtime.h>
#include <math.h>

#define A_    16
#define N_    1000
#define F_    16
#define E_    16000
#define D_    128
#define SEG_  8           // scan segments (one block each, private LDS histogram)
#define EPB   2000        // edges per scan block: 8*2000 = 16000
#define CAPS  16          // per-(node,segment) capacity (mean 2, ~9 sigma)
#define CAP_  48          // total in-degree cap (Binomial mean 16, 8 sigma)
#define MAXS  49          // slot 0 = self, 1..48 = in-edges of agent node
#define NB_A1 196         // attn1 blocks: 784 waves = 16*49
#define NB_GH 24          // gh blocks (6144 = 16*384 row-dots)

__device__ __forceinline__ float lrelu(float v){ return v > 0.0f ? v : 0.2f*v; }
__device__ __forceinline__ float sigm(float x){ return 1.0f/(1.0f + expf(-x)); }

__device__ __forceinline__ int seg_total(const int* __restrict__ ncnt, int v){
  int t = 0;
  #pragma unroll
  for (int s = 0; s < SEG_; ++s) t += ncnt[v*SEG_ + s];
  return t;
}
// ordinal j (0-based) among v's in-edges -> source node id
__device__ __forceinline__ int seg_lookup(const int* __restrict__ ncnt,
                                          const int* __restrict__ nbrs, int v, int j){
  int base = 0, r = 0;
  bool done = false;
  #pragma unroll
  for (int s = 0; s < SEG_; ++s){
    int c = ncnt[v*SEG_ + s];
    if (!done && j < base + c){ r = nbrs[(v*SEG_ + s)*CAPS + (j - base)]; done = true; }
    base += c;
  }
  return r;
}

// ---- D1: blocks 0-7 segmented edge scan | blocks 8-23 agent flags --------
__global__ void __launch_bounds__(256) k_pre(
    const int* __restrict__ ei, const float* __restrict__ nf,
    int* __restrict__ ncnt, int* __restrict__ nbrs,
    int* __restrict__ agent_node){
  const int bid = blockIdx.x, tid = threadIdx.x;

  if (bid < SEG_){                     // private-LDS histogram over own slice
    __shared__ int lcnt[N_];
    for (int t = tid; t < N_; t += 256) lcnt[t] = 0;
    __syncthreads();
    const int base = bid*EPB;
    #pragma unroll
    for (int r = 0; r < 8; ++r){
      const int e = base + r*256 + tid;
      if (e < base + EPB && e < E_){
        int src = ei[e], dst = ei[E_ + e];
        int pos = atomicAdd(&lcnt[dst], 1);
        if (pos < CAPS) nbrs[(dst*SEG_ + bid)*CAPS + pos] = src;
      }
    }
    __syncthreads();
    for (int t = tid; t < N_; t += 256) ncnt[t*SEG_ + bid] = min(lcnt[t], CAPS);
  } else {                             // agent flag scan (one block per agent)
    const int a = bid - SEG_;
    for (int t = tid; t < N_; t += 256)
      if (nf[(size_t)(a*N_ + t)*F_] == 1.0f) agent_node[a] = t;
  }
}

// ---- D2: blocks 0-195 = layer-1 GATv2 + LN/ReLU + fused xl2/xr2 GEMV;
//          blocks 196-219 = gh = bhh + Whh @ rnn_state --------------------
__global__ void __launch_bounds__(256) k_mid(
    const float* __restrict__ nf, const int* __restrict__ agent_node,
    const int* __restrict__ ncnt, const int* __restrict__ nbrs,
    const float* __restrict__ Wl1, const float* __restrict__ Wr1,
    const float* __restrict__ att1, const float* __restrict__ b1,
    const float* __restrict__ lnw, const float* __restrict__ lnb,
    const float* __restrict__ Wl2, const float* __restrict__ Wr2,
    const float* __restrict__ hs, const float* __restrict__ Whh,
    const float* __restrict__ bhh,
    float* __restrict__ xl2_c, float* __restrict__ xr2g,
    float* __restrict__ ghb){
  const int tid  = threadIdx.x;

  if (blockIdx.x >= NB_A1){            // ---- gh rows (independent of scan)
    const int rg = (blockIdx.x - NB_A1)*256 + tid;   // 0..6143
    const int a = rg/384, r = rg - a*384;
    const float4* w4 = (const float4*)&Whh[r*D_];
    const float4* x4 = (const float4*)&hs[a*D_];
    float acc = bhh[r];
    #pragma unroll
    for (int k = 0; k < D_/4; ++k){
      float4 w = w4[k], x = x4[k];
      acc += w.x*x.x + w.y*x.y + w.z*x.z + w.w*x.w;
    }
    ghb[a*384 + r] = acc;
    return;
  }

  const int lane = tid & 63;
  const int wv   = tid >> 6;
  const int wid  = blockIdx.x*4 + wv;
  const int a = wid / MAXS;
  const int i = wid - a*MAXS;
  const int d_a  = agent_node[a];
  const int dega = min(seg_total(ncnt, d_a), CAP_);
  if (i > dega) return;
  const int v   = (i == 0) ? d_a : seg_lookup(ncnt, nbrs, d_a, i-1);
  const int deg = min(seg_total(ncnt, v), CAP_);
  const int c0  = lane*2;

  __shared__ float feat[4][MAXS*F_];
  float* fb = feat[wv];

  int nid = (lane < deg) ? seg_lookup(ncnt, nbrs, v, lane) : 0;
  for (int t = lane; t < (deg+1)*4; t += 64){     // rows: 0=self, 1..deg
    int j = t >> 2, q = (t & 3)*4;
    int s = (j == 0) ? v : __shfl(nid, j-1);
    *(float4*)&fb[j*F_ + q] = *(const float4*)&nf[((size_t)a*N_ + s)*F_ + q];
  }
  asm volatile("s_waitcnt lgkmcnt(0)" ::: "memory");

  float wl0[F_], wl1c[F_];
  #pragma unroll
  for (int k = 0; k < F_; ++k){
    float2 w = *(const float2*)&Wl1[k*D_ + c0];
    wl0[k] = w.x; wl1c[k] = w.y;
  }
  float xr0 = 0.f, xr1 = 0.f;
  #pragma unroll
  for (int k = 0; k < F_; ++k){
    float2 w = *(const float2*)&Wr1[k*D_ + c0];
    float xv = fb[k];
    xr0 += xv*w.x; xr1 += xv*w.y;
  }
  const int head = lane >> 4;
  const float at0 = att1[head*32 + (c0 & 31)];
  const float at1 = att1[head*32 + ((c0+1) & 31)];

  float m = -INFINITY, ls = 0.f, ac0 = 0.f, ac1 = 0.f;
  for (int j = 0; j <= deg; ++j){
    const float* fr = &fb[j*F_];
    float xl0 = 0.f, xl1 = 0.f;
    #pragma unroll
    for (int k = 0; k < F_; k += 4){
      float4 xv = *(const float4*)&fr[k];
      xl0 += xv.x*wl0[k]  + xv.y*wl0[k+1]  + xv.z*wl0[k+2]  + xv.w*wl0[k+3];
      xl1 += xv.x*wl1c[k] + xv.y*wl1c[k+1] + xv.z*wl1c[k+2] + xv.w*wl1c[k+3];
    }
    float t = lrelu(xl0 + xr0)*at0 + lrelu(xl1 + xr1)*at1;
    t += __shfl_xor(t,1); t += __shfl_xor(t,2);
    t += __shfl_xor(t,4); t += __shfl_xor(t,8);         // 16-lane head groups
    float mn = fmaxf(m, t);
    float sc = expf(m - mn), p = expf(t - mn);
    ls = ls*sc + p; ac0 = ac0*sc + p*xl0; ac1 = ac1*sc + p*xl1;
    m = mn;
  }
  float inv = 1.0f/ls;
  float v0 = ac0*inv + b1[c0], v1 = ac1*inv + b1[c0+1];
  float ss = v0 + v1;
  ss += __shfl_xor(ss,1); ss += __shfl_xor(ss,2); ss += __shfl_xor(ss,4);
  ss += __shfl_xor(ss,8); ss += __shfl_xor(ss,16); ss += __shfl_xor(ss,32);
  float mu = ss*(1.0f/D_);
  float d0 = v0 - mu, d1 = v1 - mu;
  float vs = d0*d0 + d1*d1;
  vs += __shfl_xor(vs,1); vs += __shfl_xor(vs,2); vs += __shfl_xor(vs,4);
  vs += __shfl_xor(vs,8); vs += __shfl_xor(vs,16); vs += __shfl_xor(vs,32);
  float rinv = rsqrtf(vs*(1.0f/D_) + 1e-5f);
  float h0 = fmaxf(d0*rinv*lnw[c0]   + lnb[c0],   0.0f);
  float h1 = fmaxf(d1*rinv*lnw[c0+1] + lnb[c0+1], 0.0f);

  // ---- fused epilogue: park h row in wave-local LDS, xl2 = h @ Wl2 -------
  fb[c0] = h0; fb[c0+1] = h1;
  asm volatile("s_waitcnt lgkmcnt(0)" ::: "memory");    // wave-coherent LDS

  float xa0 = 0.f, xa1 = 0.f;
  #pragma unroll 8
  for (int k = 0; k < D_; k += 4){
    float4 hv = *(const float4*)&fb[k];
    float2 w0 = *(const float2*)&Wl2[(k+0)*D_ + c0];
    float2 w1 = *(const float2*)&Wl2[(k+1)*D_ + c0];
    float2 w2 = *(const float2*)&Wl2[(k+2)*D_ + c0];
    float2 w3 = *(const float2*)&Wl2[(k+3)*D_ + c0];
    xa0 += hv.x*w0.x + hv.y*w1.x + hv.z*w2.x + hv.w*w3.x;
    xa1 += hv.x*w0.y + hv.y*w1.y + hv.z*w2.y + hv.w*w3.y;
  }
  *(float2*)&xl2_c[((size_t)a*MAXS + i)*D_ + c0] = make_float2(xa0, xa1);

  if (i == 0){                         // agent slot also produces xr2
    float xb0 = 0.f, xb1 = 0.f;
    #pragma unroll 8
    for (int k = 0; k < D_; k += 4){
      float4 hv = *(const float4*)&fb[k];
      float2 w0 = *(const float2*)&Wr2[(k+0)*D_ + c0];
      float2 w1 = *(const float2*)&Wr2[(k+1)*D_ + c0];
      float2 w2 = *(const float2*)&Wr2[(k+2)*D_ + c0];
      float2 w3 = *(const float2*)&Wr2[(k+3)*D_ + c0];
      xb0 += hv.x*w0.x + hv.y*w1.x + hv.z*w2.x + hv.w*w3.x;
      xb1 += hv.x*w0.y + hv.y*w1.y + hv.z*w2.y + hv.w*w3.y;
    }
    *(float2*)&xr2g[a*D_ + c0] = make_float2(xb0, xb1);
  }
}

// ---- D3: per-agent tail: attn2 + gi + GRU + heads (T1 eliminated) --------
__global__ void __launch_bounds__(1024) k_tail(
    const float* __restrict__ xl2_c, const float* __restrict__ xr2g,
    const float* __restrict__ ghb,
    const int* __restrict__ agent_node, const int* __restrict__ ncnt,
    const float* __restrict__ hs, const int* __restrict__ am,
    const float* __restrict__ att2, const float* __restrict__ b2,
    const float* __restrict__ Wih, const float* __restrict__ bih,
    const float* __restrict__ Wa, const float* __restrict__ ba,
    const float* __restrict__ Wv, const float* __restrict__ bv,
    float* __restrict__ out){
  const int a    = blockIdx.x;
  const int tid  = threadIdx.x;
  const int lane = tid & 63;
  const int wv   = tid >> 6;

  __shared__ float xsl[MAXS][D_];      // xl2 rows
  __shared__ float xr2s[D_], afl[D_], ghl[3*D_], gbuf[3*D_], hsrow[D_], nh[D_];
  __shared__ float scores[64];

  const int d_a = agent_node[a];
  const int ns  = min(seg_total(ncnt, d_a), CAP_) + 1;

  // T0: stage xl2 rows + xr2 + gh + rnn_state
  for (int t = tid; t < ns*(D_/4); t += 1024){
    int j = t >> 5, q = t & 31;
    ((float4*)xsl[j])[q] = ((const float4*)&xl2_c[((size_t)a*MAXS + j)*D_])[q];
  }
  if (tid < D_) hsrow[tid] = hs[a*D_ + tid];
  else if (tid < 4*D_) ghl[tid - D_] = ghb[a*384 + (tid - D_)];
  else if (tid < 5*D_) xr2s[tid - 4*D_] = xr2g[a*D_ + (tid - 4*D_)];
  __syncthreads();

  // T2a: attention scores, wave w handles slots w, w+16, w+32, w+48
  {
    const int c0 = lane*2;
    const float xr0 = xr2s[c0], xr1 = xr2s[c0+1];
    const float at0 = att2[c0], at1 = att2[c0+1];
    for (int q = 0; q < 4; ++q){
      const int s = wv + q*16;
      if (s < ns){
        float2 xl = *(const float2*)&xsl[s][c0];
        float t = lrelu(xl.x + xr0)*at0 + lrelu(xl.y + xr1)*at1;
        t += __shfl_xor(t,1);  t += __shfl_xor(t,2);  t += __shfl_xor(t,4);
        t += __shfl_xor(t,8);  t += __shfl_xor(t,16); t += __shfl_xor(t,32);
        if (lane == 0) scores[s] = t;
      }
    }
  }
  __syncthreads();
  // T2b: softmax over ns scores (wave 0, lane-parallel)
  if (wv == 0){
    float sc = (lane < ns) ? scores[lane] : -INFINITY;
    float m = sc;
    m = fmaxf(m, __shfl_xor(m,1));  m = fmaxf(m, __shfl_xor(m,2));
    m = fmaxf(m, __shfl_xor(m,4));  m = fmaxf(m, __shfl_xor(m,8));
    m = fmaxf(m, __shfl_xor(m,16)); m = fmaxf(m, __shfl_xor(m,32));
    float p = (lane < ns) ? expf(sc - m) : 0.f;
    float s = p;
    s += __shfl_xor(s,1);  s += __shfl_xor(s,2);  s += __shfl_xor(s,4);
    s += __shfl_xor(s,8);  s += __shfl_xor(s,16); s += __shfl_xor(s,32);
    if (lane < ns) scores[lane] = p/s;           // alpha
  }
  __syncthreads();
  // T2c: weighted sum -> afl
  if (tid < D_){
    float acc = 0.f;
    for (int i = 0; i < ns; ++i) acc += scores[i]*xsl[i][tid];
    afl[tid] = acc + b2[tid];
  }
  __syncthreads();

  // T3: gi = bih + Wih @ afl — 8 lanes per row, coalesced float4 reads
  #pragma unroll
  for (int p = 0; p < 3; ++p){
    const int r  = p*128 + (tid >> 3);
    const int kk = (tid & 7)*16;
    const float4* w4 = (const float4*)&Wih[r*D_ + kk];
    float acc = 0.f;
    #pragma unroll
    for (int q = 0; q < 4; ++q){
      float4 w = w4[q];
      float4 x = *(const float4*)&afl[kk + q*4];
      acc += w.x*x.x + w.y*x.y + w.z*x.z + w.w*x.w;
    }
    acc += __shfl_xor(acc,1); acc += __shfl_xor(acc,2); acc += __shfl_xor(acc,4);
    if ((tid & 7) == 0) gbuf[r] = acc + bih[r];
  }
  __syncthreads();

  // T4: GRU elementwise
  if (tid < D_){
    float r = sigm(gbuf[tid]         + ghl[tid]);
    float z = sigm(gbuf[D_ + tid]    + ghl[D_ + tid]);
    float n = tanhf(gbuf[2*D_ + tid] + r*ghl[2*D_ + tid]);
    float nv = (1.0f - z)*n + z*hsrow[tid];
    nh[tid] = nv;
    out[272 + a*D_ + tid] = nv;                  // next_h
  }
  __syncthreads();

  // T5: heads, wave-parallel
  if (wv == 0){
    const int j = lane & 15, q = lane >> 4;      // action j, k-quarter q
    float acc = 0.f;
    #pragma unroll 8
    for (int k = q*32; k < q*32 + 32; ++k) acc += nh[k]*Wa[k*16 + j];
    acc += __shfl_xor(acc,16); acc += __shfl_xor(acc,32);
    if (lane < 16){
      float lg = acc + ba[j];
      if (am[a*16 + j] == 0) lg = -1e8f;
      out[a*16 + j] = lg;                        // logits
    }
  } else if (wv == 1){
    const int c0 = lane*2;
    float acc = nh[c0]*Wv[c0] + nh[c0+1]*Wv[c0+1];
    acc += __shfl_xor(acc,1);  acc += __shfl_xor(acc,2);  acc += __shfl_xor(acc,4);
    acc += __shfl_xor(acc,8);  acc += __shfl_xor(acc,16); acc += __shfl_xor(acc,32);
    if (lane == 0) out[256 + a] = acc + bv[0];   // values
  }
}

// ---------------------------------------------------------------------------
extern "C" void kernel_launch(void* const* d_in, const int* in_sizes, int n_in,
                              void* d_out, int out_size, void* d_ws, size_t ws_size,
                              hipStream_t stream){
  const float* nf   = (const float*)d_in[0];
  const int*   ei   = (const int*)  d_in[1];
  const float* hs   = (const float*)d_in[2];
  const int*   am   = (const int*)  d_in[3];
  const float* Wl1  = (const float*)d_in[4];
  const float* Wr1  = (const float*)d_in[5];
  const float* att1 = (const float*)d_in[6];
  const float* b1   = (const float*)d_in[7];
  const float* lnw  = (const float*)d_in[8];
  const float* lnb  = (const float*)d_in[9];
  const float* Wl2  = (const float*)d_in[10];
  const float* Wr2  = (const float*)d_in[11];
  const float* att2 = (const float*)d_in[12];
  const float* b2   = (const float*)d_in[13];
  const float* Wih  = (const float*)d_in[14];
  const float* Whh  = (const float*)d_in[15];
  const float* bih  = (const float*)d_in[16];
  const float* bhh  = (const float*)d_in[17];
  const float* Wa   = (const float*)d_in[18];
  const float* ba   = (const float*)d_in[19];
  const float* Wv   = (const float*)d_in[20];
  const float* bv   = (const float*)d_in[21];
  float* out = (float*)d_out;

  int* wsI = (int*)d_ws;
  int*   ncnt       = wsI;                      // [1000][8] ints
  int*   agent_node = wsI + 8000;               // 16 ints (pad to 8192)
  int*   nbrs       = wsI + 8192;               // [1000][8][16] ints -> ends 136192
  float* xl2_c      = (float*)(wsI + 136192);   // 16*49*128 floats -> ends 236544
  float* xr2g       = (float*)(wsI + 236544);   // 16*128 floats -> ends 238592
  float* ghb        = (float*)(wsI + 238592);   // 16*384 floats -> ends 244736

  k_pre <<<SEG_ + A_, 256, 0, stream>>>(ei, nf, ncnt, nbrs, agent_node);
  k_mid <<<NB_A1 + NB_GH, 256, 0, stream>>>(nf, agent_node, ncnt, nbrs,
                                            Wl1, Wr1, att1, b1, lnw, lnb,
                                            Wl2, Wr2, hs, Whh, bhh,
                                            xl2_c, xr2g, ghb);
  k_tail<<<A_, 1024, 0, stream>>>(xl2_c, xr2g, ghb, agent_node, ncnt, hs, am,
                                  att2, b2, Wih, bih, Wa, ba, Wv, bv, out);
}